// Round 14
// baseline (175.724 us; speedup 1.0000x reference)
//
#include <hip/hip_runtime.h>
#include <cfloat>
#include <climits>

#define BATCH 4
#define KQ    2048
#define NP    4096
#define CIN   64
#define CMID  32
#define NB    16
#define NBINS 4096   // bits >> 19 : 8 exp bits + 4 mantissa bits
#define CANDCAP 256
#define QPB   8      // queries per block in edge_prep

typedef short   bf16x8  __attribute__((ext_vector_type(8)));
typedef float   floatx4 __attribute__((ext_vector_type(4)));

__device__ __forceinline__ unsigned short f2bf(float f) {
  unsigned u = __float_as_uint(f);
  u = (u + 0x7fffu + ((u >> 16) & 1u)) >> 16;   // RNE, inputs finite
  return (unsigned short)u;
}
__device__ __forceinline__ float bf2f(unsigned short u) {
  return __uint_as_float((unsigned)u << 16);
}

// async global->LDS, 16B per lane; LDS dst = base + lane*16 (wave-uniform base)
__device__ __forceinline__ void load_lds16(const void* g, void* l) {
  __builtin_amdgcn_global_load_lds(
      (const __attribute__((address_space(1))) unsigned int*)g,
      (__attribute__((address_space(3))) unsigned int*)l, 16, 0, 0);
}

// ---------------------------------------------------------------------------
// Kernel 1: radix-select top-16 per query -> nidx[8192][16]. (R13: psum scan
// + rank pass + low-VGPR chunked loader + launch_bounds(256,8).)
// ---------------------------------------------------------------------------
__global__ __launch_bounds__(256, 8) void select_topk(
    const float* __restrict__ keys, const float* __restrict__ points,
    int* __restrict__ nidx_g) {
  __shared__ __align__(16) int hist[NBINS];   // 16 KB
  __shared__ int   psum[256];
  __shared__ float cand_d[CANDCAP];
  __shared__ int   cand_i[CANDCAP];
  __shared__ int   nidx[NB];
  __shared__ int   sel_cnt, cand_cnt, sBin, sCbelow;

  const int tid = threadIdx.x;
  const int b   = blockIdx.x >> 11;

#pragma unroll
  for (int t = 0; t < 4; ++t)
    *reinterpret_cast<int4*>(&hist[(tid + t * 256) * 4]) = int4{0, 0, 0, 0};
  if (tid == 0) { sel_cnt = 0; cand_cnt = 0; }

  const float kx = keys[blockIdx.x * 3 + 0];
  const float ky = keys[blockIdx.x * 3 + 1];
  const float kz = keys[blockIdx.x * 3 + 2];
  __syncthreads();

  // distances in 4 chunks of 4 points (3 float4 live at a time) + histogram
  const float4* pv =
      reinterpret_cast<const float4*>(points + (size_t)b * NP * 3) + (size_t)tid * 12;
  float dreg[16];
#pragma unroll
  for (int g = 0; g < 4; ++g) {
    const float4 v0 = pv[g * 3 + 0];
    const float4 v1 = pv[g * 3 + 1];
    const float4 v2 = pv[g * 3 + 2];
    const float px[4] = {v0.x, v0.w, v1.z, v2.y};
    const float py[4] = {v0.y, v1.x, v1.w, v2.z};
    const float pz[4] = {v0.z, v1.y, v2.x, v2.w};
#pragma unroll
    for (int j = 0; j < 4; ++j) {
      const float dx = px[j] - kx, dy = py[j] - ky, dz = pz[j] - kz;
      const float d  = dx * dx + dy * dy + dz * dz;
      dreg[g * 4 + j] = d;
      atomicAdd(&hist[__float_as_uint(d) >> 19], 1);
    }
  }
  __syncthreads();

  // two-level threshold scan: per-thread 16-bin sums -> wave-0 shuffle scan
  {
    const int base = tid * 16;
    int s = 0;
#pragma unroll
    for (int t = 0; t < 4; ++t) {
      const int4 hv = *reinterpret_cast<const int4*>(&hist[base + t * 4]);
      s += hv.x + hv.y + hv.z + hv.w;
    }
    psum[tid] = s;
  }
  __syncthreads();

  if (tid < 64) {
    const int q = psum[tid * 4] + psum[tid * 4 + 1] + psum[tid * 4 + 2] + psum[tid * 4 + 3];
    int incl = q;
#pragma unroll
    for (int off = 1; off < 64; off <<= 1) {
      int u = __shfl_up(incl, off);
      if (tid >= off) incl += u;
    }
    unsigned long long bal = __ballot(incl >= NB);
    int firstlane = __ffsll((long long)bal) - 1;
    if (tid == firstlane) {
      int cum = incl - q;
      int bin = -1;
      for (int t = 0; t < 4 && bin < 0; ++t) {
        const int ps = psum[tid * 4 + t];
        if (cum + ps >= NB) {
          const int b0 = (tid * 4 + t) * 16;
          for (int j = 0; j < 16; ++j) {
            const int h = hist[b0 + j];
            if (cum + h >= NB) { bin = b0 + j; break; }
            cum += h;
          }
        } else cum += ps;
      }
      sBin = bin; sCbelow = cum;
    }
  }
  __syncthreads();

  const unsigned B = (unsigned)sBin;
#pragma unroll
  for (int j = 0; j < 16; ++j) {
    const int i = tid * 16 + j;
    const unsigned bk = __float_as_uint(dreg[j]) >> 19;
    if (bk < B) {
      int pos = atomicAdd(&sel_cnt, 1);
      nidx[pos] = i;
    } else if (bk == B) {
      int pos = atomicAdd(&cand_cnt, 1);
      if (pos < CANDCAP) { cand_d[pos] = dreg[j]; cand_i[pos] = i; }
    }
  }
  __syncthreads();

  // boundary-bin rank pass: rank(j) = #{k: (d_k,i_k) < (d_j,i_j)}
  {
    const int rem = NB - sCbelow;
    const int cc  = min(cand_cnt, CANDCAP);
    for (int j = tid; j < cc; j += 256) {
      const float dj = cand_d[j]; const int ij = cand_i[j];
      int rank = 0;
      for (int k = 0; k < cc; ++k) {
        const float dk = cand_d[k]; const int ik = cand_i[k];
        rank += (dk < dj || (dk == dj && ik < ij)) ? 1 : 0;
      }
      if (rank < rem) nidx[sCbelow + rank] = ij;
    }
  }
  __syncthreads();

  if (tid < NB) nidx_g[blockIdx.x * NB + tid] = nidx[tid];
}

// ---------------------------------------------------------------------------
// Kernel 2: edge MLP + aggregation -> E bf16, weight transposes folded in.
// (unchanged from R10..R13)
// ---------------------------------------------------------------------------
__global__ __launch_bounds__(256) void edge_prep(
    const float* __restrict__ keys, const float* __restrict__ points,
    const float* __restrict__ feats, const int* __restrict__ nidx_g,
    const float* __restrict__ wc0_W, const float* __restrict__ wc0_b,
    const float* __restrict__ wc1_W, const float* __restrict__ wc1_b,
    const float* __restrict__ wc2_W, const float* __restrict__ wc2_b,
    const float* __restrict__ fc0_W, const float* __restrict__ fc1_W,
    unsigned short* __restrict__ W0T, unsigned short* __restrict__ W1T,
    unsigned short* __restrict__ E) {
  __shared__ __align__(16) float w0[96], b0v[32], w1[1024], b1v[32], w2[1024], b2v[32];
  __shared__ int   idx_s[QPB * NB];                              // 512 B
  __shared__ __align__(16) unsigned short m_bf[QPB * NB][40];    // 10 KB
  __shared__ __align__(16) char u_mem[128 * 144];                // 18 KB union
  float (*h2_all)[36]        = reinterpret_cast<float(*)[36]>(u_mem);   // 144 B rows
  unsigned short (*f_bf)[72] = reinterpret_cast<unsigned short(*)[72]>(u_mem);
  float (*tt)[33]            = reinterpret_cast<float(*)[33]>(u_mem);

  const int tid = threadIdx.x;
  const int bid = blockIdx.x;
  const int q0  = bid * QPB;
  const int b   = q0 >> 11;

  // ---- folded weight transposes (f32 [K][N] -> bf16 [N][K]) ----
  if (bid < 544) {
    const float* W; unsigned short* WT; int K, N, k0, n0;
    if (bid < 512) { W = fc0_W; WT = W0T; K = 2048; N = 256;
                     k0 = (bid >> 3) * 32; n0 = (bid & 7) * 32; }
    else           { W = fc1_W; WT = W1T; K = 256;  N = 128;
                     k0 = ((bid - 512) >> 2) * 32; n0 = ((bid - 512) & 3) * 32; }
    const int tx = tid & 31, ty = tid >> 5;
#pragma unroll
    for (int p = 0; p < 4; ++p)
      tt[ty + p * 8][tx] = W[(size_t)(k0 + ty + p * 8) * N + n0 + tx];
    __syncthreads();
#pragma unroll
    for (int p = 0; p < 4; ++p)
      WT[(size_t)(n0 + ty + p * 8) * K + k0 + tx] = f2bf(tt[tx][ty + p * 8]);
    __syncthreads();   // u_mem free again
  }

  // ---- stage tiny MLP weights + neighbor indices ----
  if (tid < 96) w0[tid] = wc0_W[tid];
  for (int i = tid; i < 1024; i += 256) { w1[i] = wc1_W[i]; w2[i] = wc2_W[i]; }
  if (tid < 32) { b0v[tid] = wc0_b[tid]; b1v[tid] = wc1_b[tid]; b2v[tid] = wc2_b[tid]; }
  if (tid < QPB * NB) idx_s[tid] = nidx_g[q0 * NB + tid];
  __syncthreads();

  // ---- MLP: thread (edge, half) computes h1 fully, h2 for 16 outputs ----
  const int edge = tid & 127;
  const int half = tid >> 7;
  const int ob   = half * 16;
  const int qe   = edge >> 4;
  const int idx  = idx_s[edge];
  {
    const float* p  = points + ((size_t)b * NP + idx) * 3;
    const float* kq = keys + (size_t)(q0 + qe) * 3;
    const float rx = p[0] - kq[0], ry = p[1] - kq[1], rz = p[2] - kq[2];

    // h1: broadcast float4 weight reads
    float h1[32];
#pragma unroll
    for (int o4 = 0; o4 < 8; ++o4) {
      const float4 a = *reinterpret_cast<const float4*>(&w0[o4 * 4]);
      const float4 c = *reinterpret_cast<const float4*>(&w0[32 + o4 * 4]);
      const float4 d = *reinterpret_cast<const float4*>(&w0[64 + o4 * 4]);
      const float4 e = *reinterpret_cast<const float4*>(&b0v[o4 * 4]);
      h1[o4 * 4 + 0] = fmaxf(0.f, rx * a.x + ry * c.x + rz * d.x + e.x);
      h1[o4 * 4 + 1] = fmaxf(0.f, rx * a.y + ry * c.y + rz * d.y + e.y);
      h1[o4 * 4 + 2] = fmaxf(0.f, rx * a.z + ry * c.z + rz * d.z + e.z);
      h1[o4 * 4 + 3] = fmaxf(0.f, rx * a.w + ry * c.w + rz * d.w + e.w);
    }

    // h2: hoist h1[i], broadcast float4 w1-row reads, 16 reg accumulators
    float acc2[16];
#pragma unroll
    for (int j = 0; j < 16; ++j) acc2[j] = b1v[ob + j];
#pragma unroll
    for (int i = 0; i < 32; ++i) {
      const float hv = h1[i];
#pragma unroll
      for (int j4 = 0; j4 < 4; ++j4) {
        const float4 w = *reinterpret_cast<const float4*>(&w1[i * 32 + ob + j4 * 4]);
        acc2[j4 * 4 + 0] += hv * w.x;
        acc2[j4 * 4 + 1] += hv * w.y;
        acc2[j4 * 4 + 2] += hv * w.z;
        acc2[j4 * 4 + 3] += hv * w.w;
      }
    }
#pragma unroll
    for (int j4 = 0; j4 < 4; ++j4) {
      float4 o4v;
      o4v.x = fmaxf(acc2[j4 * 4 + 0], 0.f);
      o4v.y = fmaxf(acc2[j4 * 4 + 1], 0.f);
      o4v.z = fmaxf(acc2[j4 * 4 + 2], 0.f);
      o4v.w = fmaxf(acc2[j4 * 4 + 3], 0.f);
      *reinterpret_cast<float4*>(&h2_all[edge][ob + j4 * 4]) = o4v;
    }
  }
  __syncthreads();

  // ---- m: hoist h2, broadcast float4 w2-row reads ----
  float mo[16];
#pragma unroll
  for (int j = 0; j < 16; ++j) mo[j] = b2v[ob + j];
#pragma unroll
  for (int i = 0; i < 32; ++i) {
    const float hv = h2_all[edge][i];
#pragma unroll
    for (int j4 = 0; j4 < 4; ++j4) {
      const float4 w = *reinterpret_cast<const float4*>(&w2[i * 32 + ob + j4 * 4]);
      mo[j4 * 4 + 0] += hv * w.x;
      mo[j4 * 4 + 1] += hv * w.y;
      mo[j4 * 4 + 2] += hv * w.z;
      mo[j4 * 4 + 3] += hv * w.w;
    }
  }
  // write m (bf16 pairs packed into dwords) — separate LDS region, pre-barrier
#pragma unroll
  for (int j = 0; j < 8; ++j) {
    const unsigned lo = f2bf(mo[2 * j]), hi = f2bf(mo[2 * j + 1]);
    *reinterpret_cast<unsigned*>(&m_bf[edge][ob + 2 * j]) = lo | (hi << 16);
  }
  __syncthreads();   // h2 region dead from here; f staging reuses u_mem

  // ---- stage neighbor features bf16: 128 rows x 16 float4-chunks ----
#pragma unroll
  for (int t = 0; t < 8; ++t) {
    const int task = tid + t * 256;          // 0..2047
    const int row = task >> 4, ch = task & 15;
    const float4 v = *reinterpret_cast<const float4*>(
        feats + ((size_t)b * NP + idx_s[row]) * CIN + ch * 4);
    ushort4 o4;
    o4.x = f2bf(v.x); o4.y = f2bf(v.y); o4.z = f2bf(v.z); o4.w = f2bf(v.w);
    *reinterpret_cast<ushort4*>(&f_bf[row][ch * 4]) = o4;
  }
  __syncthreads();

  // ---- e-comp: wave -> q, lane -> (mg: 4 mids, co: 8 ch), 2 q-iters ----
  const int wv = tid >> 6, lane = tid & 63;
  const int co = lane & 7, mg = lane >> 3;
#pragma unroll
  for (int it = 0; it < 2; ++it) {
    const int q = wv + it * 4;
    float acc[4][8] = {};
#pragma unroll
    for (int n = 0; n < 16; ++n) {
      const int row = q * 16 + n;
      const ushort4 m4 = *reinterpret_cast<const ushort4*>(&m_bf[row][mg * 4]);
      const float mv[4] = {bf2f(m4.x), bf2f(m4.y), bf2f(m4.z), bf2f(m4.w)};
      const uint4 fv = *reinterpret_cast<const uint4*>(&f_bf[row][co * 8]);
      float fc[8];
      fc[0] = __uint_as_float(fv.x << 16); fc[1] = __uint_as_float(fv.x & 0xffff0000u);
      fc[2] = __uint_as_float(fv.y << 16); fc[3] = __uint_as_float(fv.y & 0xffff0000u);
      fc[4] = __uint_as_float(fv.z << 16); fc[5] = __uint_as_float(fv.z & 0xffff0000u);
      fc[6] = __uint_as_float(fv.w << 16); fc[7] = __uint_as_float(fv.w & 0xffff0000u);
#pragma unroll
      for (int i = 0; i < 4; ++i)
#pragma unroll
        for (int j = 0; j < 8; ++j) acc[i][j] += mv[i] * fc[j];
    }
    unsigned short* Eq = E + (size_t)(q0 + q) * 2048;
#pragma unroll
    for (int i = 0; i < 4; ++i) {
      const int mid = mg * 4 + i;
      uint4 o;
      o.x = (unsigned)f2bf(acc[i][0]) | ((unsigned)f2bf(acc[i][1]) << 16);
      o.y = (unsigned)f2bf(acc[i][2]) | ((unsigned)f2bf(acc[i][3]) << 16);
      o.z = (unsigned)f2bf(acc[i][4]) | ((unsigned)f2bf(acc[i][5]) << 16);
      o.w = (unsigned)f2bf(acc[i][6]) | ((unsigned)f2bf(acc[i][7]) << 16);
      *reinterpret_cast<uint4*>(&Eq[mid * 64 + co * 8]) = o;
    }
  }
}

// ---------------------------------------------------------------------------
// Kernel 3: gemm1, RETILED 128x64 (M x N). Grid = 256 blocks (64 m-tiles x
// 4 n-tiles), XCD swizzle keeps an E-slab's 4 n-tiles on one XCD. 2x2 wave
// layout, each wave 64x32 (4x2 frags) -> 8 MFMA per 6 ds_read_b128 (vs 4/4
// at 64x64). LDS 48 KB -> 3 blocks/CU. Per-output K-chain identical to the
// 64x64 version -> bit-identical H.
// ---------------------------------------------------------------------------
__global__ __launch_bounds__(256) void gemm1_big(
    const unsigned short* __restrict__ A,   // [8192][2048] bf16
    const unsigned short* __restrict__ Bt,  // [256][2048]  bf16
    const float* __restrict__ bias,
    unsigned short* __restrict__ C) {       // [8192][256] bf16 (relu)
  __shared__ __align__(16) unsigned short Al[128 * 128];  // 32 KB
  __shared__ __align__(16) unsigned short Bl[64 * 128];   // 16 KB
  const int tid  = threadIdx.x;
  const int L    = blockIdx.x;
  const int slot = L >> 3;
  const int m0   = ((L & 7) * 8 + (slot >> 2)) * 128;   // 64 m-tiles
  const int n0   = (slot & 3) * 64;                     // 4 n-tiles
  const int wv   = tid >> 6, lane = tid & 63;
  const int quad = lane >> 4, s = lane & 15;
  const int moff = (wv & 1) * 64, noff = (wv >> 1) * 32;
  const int lr   = lane >> 4, lc = lane & 15;

  floatx4 acc[4][2] = {};

  for (int k0 = 0; k0 < 2048; k0 += 128) {
    // A: 128 rows; wave wv stages rows [wv*32, wv*32+32) in 8 passes of 4
#pragma unroll
    for (int t = 0; t < 8; ++t) {
      const int R0 = wv * 32 + t * 4;
      const int r  = R0 + lr;
      const int gc = lc ^ (r & 7);
      load_lds16(A + (size_t)(m0 + r) * 2048 + k0 + gc * 8, &Al[R0 * 128]);
    }
    // B: 64 rows; wave stages rows [wv*16, wv*16+16) in 4 passes of 4
#pragma unroll
    for (int t = 0; t < 4; ++t) {
      const int R0 = wv * 16 + t * 4;
      const int r  = R0 + lr;
      const int gc = lc ^ (r & 7);
      load_lds16(Bt + (size_t)(n0 + r) * 2048 + k0 + gc * 8, &Bl[R0 * 128]);
    }
    __syncthreads();
#pragma unroll
    for (int h = 0; h < 4; ++h) {
      bf16x8 af[4], bfr[2];
#pragma unroll
      for (int i = 0; i < 4; ++i) {
        const int r = moff + i * 16 + s;
        af[i] = *reinterpret_cast<const bf16x8*>(
            &Al[(size_t)r * 128 + ((((h << 2) | quad) ^ (r & 7)) << 3)]);
      }
#pragma unroll
      for (int j = 0; j < 2; ++j) {
        const int r = noff + j * 16 + s;
        bfr[j] = *reinterpret_cast<const bf16x8*>(
            &Bl[(size_t)r * 128 + ((((h << 2) | quad) ^ (r & 7)) << 3)]);
      }
#pragma unroll
      for (int i = 0; i < 4; ++i)
#pragma unroll
        for (int j = 0; j < 2; ++j)
          acc[i][j] = __builtin_amdgcn_mfma_f32_16x16x32_bf16(af[i], bfr[j], acc[i][j], 0, 0, 0);
    }
    __syncthreads();
  }

#pragma unroll
  for (int i = 0; i < 4; ++i)
#pragma unroll
    for (int j = 0; j < 2; ++j) {
      const int col = n0 + noff + j * 16 + s;
      const float bv = bias[col];
#pragma unroll
      for (int r = 0; r < 4; ++r) {
        const int row = m0 + moff + i * 16 + quad * 4 + r;
        C[(size_t)row * 256 + col] = f2bf(fmaxf(acc[i][j][r] + bv, 0.f));
      }
    }
}

// ---------------------------------------------------------------------------
// Kernel 4: gemm2 (64x64 tile, proven path): out = H16 @ W1 + b1, fp32 out.
// ---------------------------------------------------------------------------
template <int KDIM, bool RELU, bool OUTBF16>
__global__ __launch_bounds__(256) void gemm_mfma(
    const unsigned short* __restrict__ A,   // [M][KDIM] bf16
    const unsigned short* __restrict__ Bt,  // [N][KDIM] bf16
    const float* __restrict__ bias,
    void* __restrict__ Cout, int ldc) {
  __shared__ __align__(16) unsigned short Al[64 * 128];  // 16 KB
  __shared__ __align__(16) unsigned short Bl[64 * 128];  // 16 KB
  const int tid  = threadIdx.x;
  const int m0   = blockIdx.x * 64, n0 = blockIdx.y * 64;
  const int wv   = tid >> 6, lane = tid & 63;
  const int quad = lane >> 4, s = lane & 15;
  const int moff = (wv & 1) * 32, noff = (wv >> 1) * 32;
  const int lr   = lane >> 4, lc = lane & 15;

  floatx4 acc[2][2] = {{{0.f,0.f,0.f,0.f},{0.f,0.f,0.f,0.f}},
                       {{0.f,0.f,0.f,0.f},{0.f,0.f,0.f,0.f}}};

  for (int k0 = 0; k0 < KDIM; k0 += 128) {
#pragma unroll
    for (int t = 0; t < 4; ++t) {
      const int R0 = wv * 16 + t * 4;
      const int r  = R0 + lr;
      const int gc = lc ^ (r & 7);
      load_lds16(A  + (size_t)(m0 + r) * KDIM + k0 + gc * 8, &Al[R0 * 128]);
      load_lds16(Bt + (size_t)(n0 + r) * KDIM + k0 + gc * 8, &Bl[R0 * 128]);
    }
    __syncthreads();
#pragma unroll
    for (int h = 0; h < 4; ++h) {
      bf16x8 af[2], bfr[2];
#pragma unroll
      for (int i = 0; i < 2; ++i) {
        const int r = moff + i * 16 + s;
        af[i] = *reinterpret_cast<const bf16x8*>(
            &Al[(size_t)r * 128 + ((((h << 2) | quad) ^ (r & 7)) << 3)]);
      }
#pragma unroll
      for (int j = 0; j < 2; ++j) {
        const int r = noff + j * 16 + s;
        bfr[j] = *reinterpret_cast<const bf16x8*>(
            &Bl[(size_t)r * 128 + ((((h << 2) | quad) ^ (r & 7)) << 3)]);
      }
#pragma unroll
      for (int i = 0; i < 2; ++i)
#pragma unroll
        for (int j = 0; j < 2; ++j)
          acc[i][j] = __builtin_amdgcn_mfma_f32_16x16x32_bf16(af[i], bfr[j], acc[i][j], 0, 0, 0);
    }
    __syncthreads();
  }

#pragma unroll
  for (int i = 0; i < 2; ++i)
#pragma unroll
    for (int j = 0; j < 2; ++j) {
      const int col = n0 + noff + j * 16 + s;
      const float bv = bias[col];
#pragma unroll
      for (int r = 0; r < 4; ++r) {
        const int row = m0 + moff + i * 16 + quad * 4 + r;
        float v = acc[i][j][r] + bv;
        if (RELU) v = fmaxf(v, 0.f);
        if (OUTBF16)
          ((unsigned short*)Cout)[(size_t)row * ldc + col] = f2bf(v);
        else
          ((float*)Cout)[(size_t)row * ldc + col] = v;
      }
    }
}

// ---------------------------------------------------------------------------
extern "C" void kernel_launch(void* const* d_in, const int* in_sizes, int n_in,
                              void* d_out, int out_size, void* d_ws, size_t ws_size,
                              hipStream_t stream) {
  const float* keys   = (const float*)d_in[0];
  const float* points = (const float*)d_in[1];
  const float* feats  = (const float*)d_in[2];
  const float* wc0_W  = (const float*)d_in[3];
  const float* wc0_b  = (const float*)d_in[4];
  const float* wc1_W  = (const float*)d_in[5];
  const float* wc1_b  = (const float*)d_in[6];
  const float* wc2_W  = (const float*)d_in[7];
  const float* wc2_b  = (const float*)d_in[8];
  const float* fc0_W  = (const float*)d_in[9];
  const float* fc0_b  = (const float*)d_in[10];
  const float* fc1_W  = (const float*)d_in[11];
  const float* fc1_b  = (const float*)d_in[12];
  float* out = (float*)d_out;

  const int M = BATCH * KQ;   // 8192
  char* ws = (char*)d_ws;
  unsigned short* E    = (unsigned short*)(ws);                    // 32 MB
  unsigned short* H16  = (unsigned short*)(ws + (size_t)33554432); //  4 MB
  unsigned short* W0T  = (unsigned short*)(ws + (size_t)37748736); //  1 MB
  unsigned short* W1T  = (unsigned short*)(ws + (size_t)38797312); // 64 KB
  int*            nidx = (int*)(ws + (size_t)38862848);            // 512 KB

  select_topk<<<M, 256, 0, stream>>>(keys, points, nidx);
  edge_prep<<<M / QPB, 256, 0, stream>>>(keys, points, feats, nidx,
                                         wc0_W, wc0_b, wc1_W, wc1_b, wc2_W, wc2_b,
                                         fc0_W, fc1_W, W0T, W1T, E);
  gemm1_big<<<256, 256, 0, stream>>>(E, W0T, fc0_b, H16);
  gemm_mfma<256, false, false><<<dim3(M / 64, 2), 256, 0, stream>>>(H16, W1T, fc1_b, out, 128);
}

// Round 15
// 166.927 us; speedup vs baseline: 1.0527x; 1.0527x over previous
//
#include <hip/hip_runtime.h>
#include <cfloat>
#include <climits>

#define BATCH 4
#define KQ    2048
#define NP    4096
#define CIN   64
#define CMID  32
#define NB    16
#define NBINS 4096   // bits >> 19 : 8 exp bits + 4 mantissa bits
#define CANDCAP 256
#define QPB   8      // queries per block in edge_prep

typedef short   bf16x8  __attribute__((ext_vector_type(8)));
typedef float   floatx4 __attribute__((ext_vector_type(4)));

__device__ __forceinline__ unsigned short f2bf(float f) {
  unsigned u = __float_as_uint(f);
  u = (u + 0x7fffu + ((u >> 16) & 1u)) >> 16;   // RNE, inputs finite
  return (unsigned short)u;
}
__device__ __forceinline__ float bf2f(unsigned short u) {
  return __uint_as_float((unsigned)u << 16);
}

// async global->LDS, 16B per lane; LDS dst = base + lane*16 (wave-uniform base)
__device__ __forceinline__ void load_lds16(const void* g, void* l) {
  __builtin_amdgcn_global_load_lds(
      (const __attribute__((address_space(1))) unsigned int*)g,
      (__attribute__((address_space(3))) unsigned int*)l, 16, 0, 0);
}

// ---------------------------------------------------------------------------
// Kernel 1: radix-select top-16 per query -> nidx[8192][16]. R13: psum scan
// (conflict-free layout) + parallel rank pass + low-VGPR chunked loader +
// launch_bounds(256,8). Set-only semantics; boundary ties -> lower index.
// ---------------------------------------------------------------------------
__global__ __launch_bounds__(256, 8) void select_topk(
    const float* __restrict__ keys, const float* __restrict__ points,
    int* __restrict__ nidx_g) {
  __shared__ __align__(16) int hist[NBINS];   // 16 KB
  __shared__ int   psum[256];
  __shared__ float cand_d[CANDCAP];
  __shared__ int   cand_i[CANDCAP];
  __shared__ int   nidx[NB];
  __shared__ int   sel_cnt, cand_cnt, sBin, sCbelow;

  const int tid = threadIdx.x;
  const int b   = blockIdx.x >> 11;

#pragma unroll
  for (int t = 0; t < 4; ++t)
    *reinterpret_cast<int4*>(&hist[(tid + t * 256) * 4]) = int4{0, 0, 0, 0};
  if (tid == 0) { sel_cnt = 0; cand_cnt = 0; }

  const float kx = keys[blockIdx.x * 3 + 0];
  const float ky = keys[blockIdx.x * 3 + 1];
  const float kz = keys[blockIdx.x * 3 + 2];
  __syncthreads();

  // distances in 4 chunks of 4 points (3 float4 live at a time) + histogram
  const float4* pv =
      reinterpret_cast<const float4*>(points + (size_t)b * NP * 3) + (size_t)tid * 12;
  float dreg[16];
#pragma unroll
  for (int g = 0; g < 4; ++g) {
    const float4 v0 = pv[g * 3 + 0];
    const float4 v1 = pv[g * 3 + 1];
    const float4 v2 = pv[g * 3 + 2];
    const float px[4] = {v0.x, v0.w, v1.z, v2.y};
    const float py[4] = {v0.y, v1.x, v1.w, v2.z};
    const float pz[4] = {v0.z, v1.y, v2.x, v2.w};
#pragma unroll
    for (int j = 0; j < 4; ++j) {
      const float dx = px[j] - kx, dy = py[j] - ky, dz = pz[j] - kz;
      const float d  = dx * dx + dy * dy + dz * dz;
      dreg[g * 4 + j] = d;
      atomicAdd(&hist[__float_as_uint(d) >> 19], 1);
    }
  }
  __syncthreads();

  // two-level threshold scan: per-thread 16-bin sums -> wave-0 shuffle scan
  {
    const int base = tid * 16;
    int s = 0;
#pragma unroll
    for (int t = 0; t < 4; ++t) {
      const int4 hv = *reinterpret_cast<const int4*>(&hist[base + t * 4]);
      s += hv.x + hv.y + hv.z + hv.w;
    }
    psum[tid] = s;
  }
  __syncthreads();

  if (tid < 64) {
    const int q = psum[tid * 4] + psum[tid * 4 + 1] + psum[tid * 4 + 2] + psum[tid * 4 + 3];
    int incl = q;
#pragma unroll
    for (int off = 1; off < 64; off <<= 1) {
      int u = __shfl_up(incl, off);
      if (tid >= off) incl += u;
    }
    unsigned long long bal = __ballot(incl >= NB);
    int firstlane = __ffsll((long long)bal) - 1;
    if (tid == firstlane) {
      int cum = incl - q;
      int bin = -1;
      for (int t = 0; t < 4 && bin < 0; ++t) {
        const int ps = psum[tid * 4 + t];
        if (cum + ps >= NB) {
          const int b0 = (tid * 4 + t) * 16;
          for (int j = 0; j < 16; ++j) {
            const int h = hist[b0 + j];
            if (cum + h >= NB) { bin = b0 + j; break; }
            cum += h;
          }
        } else cum += ps;
      }
      sBin = bin; sCbelow = cum;
    }
  }
  __syncthreads();

  const unsigned B = (unsigned)sBin;
#pragma unroll
  for (int j = 0; j < 16; ++j) {
    const int i = tid * 16 + j;
    const unsigned bk = __float_as_uint(dreg[j]) >> 19;
    if (bk < B) {
      int pos = atomicAdd(&sel_cnt, 1);
      nidx[pos] = i;
    } else if (bk == B) {
      int pos = atomicAdd(&cand_cnt, 1);
      if (pos < CANDCAP) { cand_d[pos] = dreg[j]; cand_i[pos] = i; }
    }
  }
  __syncthreads();

  // boundary-bin rank pass: rank(j) = #{k: (d_k,i_k) < (d_j,i_j)}
  {
    const int rem = NB - sCbelow;
    const int cc  = min(cand_cnt, CANDCAP);
    for (int j = tid; j < cc; j += 256) {
      const float dj = cand_d[j]; const int ij = cand_i[j];
      int rank = 0;
      for (int k = 0; k < cc; ++k) {
        const float dk = cand_d[k]; const int ik = cand_i[k];
        rank += (dk < dj || (dk == dj && ik < ij)) ? 1 : 0;
      }
      if (rank < rem) nidx[sCbelow + rank] = ij;
    }
  }
  __syncthreads();

  if (tid < NB) nidx_g[blockIdx.x * NB + tid] = nidx[tid];
}

// ---------------------------------------------------------------------------
// Kernel 2: edge MLP + aggregation -> E bf16, weight transposes folded in.
// ---------------------------------------------------------------------------
__global__ __launch_bounds__(256) void edge_prep(
    const float* __restrict__ keys, const float* __restrict__ points,
    const float* __restrict__ feats, const int* __restrict__ nidx_g,
    const float* __restrict__ wc0_W, const float* __restrict__ wc0_b,
    const float* __restrict__ wc1_W, const float* __restrict__ wc1_b,
    const float* __restrict__ wc2_W, const float* __restrict__ wc2_b,
    const float* __restrict__ fc0_W, const float* __restrict__ fc1_W,
    unsigned short* __restrict__ W0T, unsigned short* __restrict__ W1T,
    unsigned short* __restrict__ E) {
  __shared__ __align__(16) float w0[96], b0v[32], w1[1024], b1v[32], w2[1024], b2v[32];
  __shared__ int   idx_s[QPB * NB];                              // 512 B
  __shared__ __align__(16) unsigned short m_bf[QPB * NB][40];    // 10 KB
  __shared__ __align__(16) char u_mem[128 * 144];                // 18 KB union
  float (*h2_all)[36]        = reinterpret_cast<float(*)[36]>(u_mem);   // 144 B rows
  unsigned short (*f_bf)[72] = reinterpret_cast<unsigned short(*)[72]>(u_mem);
  float (*tt)[33]            = reinterpret_cast<float(*)[33]>(u_mem);

  const int tid = threadIdx.x;
  const int bid = blockIdx.x;
  const int q0  = bid * QPB;
  const int b   = q0 >> 11;

  // ---- folded weight transposes (f32 [K][N] -> bf16 [N][K]) ----
  if (bid < 544) {
    const float* W; unsigned short* WT; int K, N, k0, n0;
    if (bid < 512) { W = fc0_W; WT = W0T; K = 2048; N = 256;
                     k0 = (bid >> 3) * 32; n0 = (bid & 7) * 32; }
    else           { W = fc1_W; WT = W1T; K = 256;  N = 128;
                     k0 = ((bid - 512) >> 2) * 32; n0 = ((bid - 512) & 3) * 32; }
    const int tx = tid & 31, ty = tid >> 5;
#pragma unroll
    for (int p = 0; p < 4; ++p)
      tt[ty + p * 8][tx] = W[(size_t)(k0 + ty + p * 8) * N + n0 + tx];
    __syncthreads();
#pragma unroll
    for (int p = 0; p < 4; ++p)
      WT[(size_t)(n0 + ty + p * 8) * K + k0 + tx] = f2bf(tt[tx][ty + p * 8]);
    __syncthreads();   // u_mem free again
  }

  // ---- stage tiny MLP weights + neighbor indices ----
  if (tid < 96) w0[tid] = wc0_W[tid];
  for (int i = tid; i < 1024; i += 256) { w1[i] = wc1_W[i]; w2[i] = wc2_W[i]; }
  if (tid < 32) { b0v[tid] = wc0_b[tid]; b1v[tid] = wc1_b[tid]; b2v[tid] = wc2_b[tid]; }
  if (tid < QPB * NB) idx_s[tid] = nidx_g[q0 * NB + tid];
  __syncthreads();

  // ---- MLP: thread (edge, half) computes h1 fully, h2 for 16 outputs ----
  const int edge = tid & 127;
  const int half = tid >> 7;
  const int ob   = half * 16;
  const int qe   = edge >> 4;
  const int idx  = idx_s[edge];
  {
    const float* p  = points + ((size_t)b * NP + idx) * 3;
    const float* kq = keys + (size_t)(q0 + qe) * 3;
    const float rx = p[0] - kq[0], ry = p[1] - kq[1], rz = p[2] - kq[2];

    // h1: broadcast float4 weight reads
    float h1[32];
#pragma unroll
    for (int o4 = 0; o4 < 8; ++o4) {
      const float4 a = *reinterpret_cast<const float4*>(&w0[o4 * 4]);
      const float4 c = *reinterpret_cast<const float4*>(&w0[32 + o4 * 4]);
      const float4 d = *reinterpret_cast<const float4*>(&w0[64 + o4 * 4]);
      const float4 e = *reinterpret_cast<const float4*>(&b0v[o4 * 4]);
      h1[o4 * 4 + 0] = fmaxf(0.f, rx * a.x + ry * c.x + rz * d.x + e.x);
      h1[o4 * 4 + 1] = fmaxf(0.f, rx * a.y + ry * c.y + rz * d.y + e.y);
      h1[o4 * 4 + 2] = fmaxf(0.f, rx * a.z + ry * c.z + rz * d.z + e.z);
      h1[o4 * 4 + 3] = fmaxf(0.f, rx * a.w + ry * c.w + rz * d.w + e.w);
    }

    // h2: hoist h1[i], broadcast float4 w1-row reads, 16 reg accumulators
    float acc2[16];
#pragma unroll
    for (int j = 0; j < 16; ++j) acc2[j] = b1v[ob + j];
#pragma unroll
    for (int i = 0; i < 32; ++i) {
      const float hv = h1[i];
#pragma unroll
      for (int j4 = 0; j4 < 4; ++j4) {
        const float4 w = *reinterpret_cast<const float4*>(&w1[i * 32 + ob + j4 * 4]);
        acc2[j4 * 4 + 0] += hv * w.x;
        acc2[j4 * 4 + 1] += hv * w.y;
        acc2[j4 * 4 + 2] += hv * w.z;
        acc2[j4 * 4 + 3] += hv * w.w;
      }
    }
#pragma unroll
    for (int j4 = 0; j4 < 4; ++j4) {
      float4 o4v;
      o4v.x = fmaxf(acc2[j4 * 4 + 0], 0.f);
      o4v.y = fmaxf(acc2[j4 * 4 + 1], 0.f);
      o4v.z = fmaxf(acc2[j4 * 4 + 2], 0.f);
      o4v.w = fmaxf(acc2[j4 * 4 + 3], 0.f);
      *reinterpret_cast<float4*>(&h2_all[edge][ob + j4 * 4]) = o4v;
    }
  }
  __syncthreads();

  // ---- m: hoist h2, broadcast float4 w2-row reads ----
  float mo[16];
#pragma unroll
  for (int j = 0; j < 16; ++j) mo[j] = b2v[ob + j];
#pragma unroll
  for (int i = 0; i < 32; ++i) {
    const float hv = h2_all[edge][i];
#pragma unroll
    for (int j4 = 0; j4 < 4; ++j4) {
      const float4 w = *reinterpret_cast<const float4*>(&w2[i * 32 + ob + j4 * 4]);
      mo[j4 * 4 + 0] += hv * w.x;
      mo[j4 * 4 + 1] += hv * w.y;
      mo[j4 * 4 + 2] += hv * w.z;
      mo[j4 * 4 + 3] += hv * w.w;
    }
  }
  // write m (bf16 pairs packed into dwords) — separate LDS region, pre-barrier
#pragma unroll
  for (int j = 0; j < 8; ++j) {
    const unsigned lo = f2bf(mo[2 * j]), hi = f2bf(mo[2 * j + 1]);
    *reinterpret_cast<unsigned*>(&m_bf[edge][ob + 2 * j]) = lo | (hi << 16);
  }
  __syncthreads();   // h2 region dead from here; f staging reuses u_mem

  // ---- stage neighbor features bf16: 128 rows x 16 float4-chunks ----
#pragma unroll
  for (int t = 0; t < 8; ++t) {
    const int task = tid + t * 256;          // 0..2047
    const int row = task >> 4, ch = task & 15;
    const float4 v = *reinterpret_cast<const float4*>(
        feats + ((size_t)b * NP + idx_s[row]) * CIN + ch * 4);
    ushort4 o4;
    o4.x = f2bf(v.x); o4.y = f2bf(v.y); o4.z = f2bf(v.z); o4.w = f2bf(v.w);
    *reinterpret_cast<ushort4*>(&f_bf[row][ch * 4]) = o4;
  }
  __syncthreads();

  // ---- e-comp: wave -> q, lane -> (mg: 4 mids, co: 8 ch), 2 q-iters ----
  const int wv = tid >> 6, lane = tid & 63;
  const int co = lane & 7, mg = lane >> 3;
#pragma unroll
  for (int it = 0; it < 2; ++it) {
    const int q = wv + it * 4;
    float acc[4][8] = {};
#pragma unroll
    for (int n = 0; n < 16; ++n) {
      const int row = q * 16 + n;
      const ushort4 m4 = *reinterpret_cast<const ushort4*>(&m_bf[row][mg * 4]);
      const float mv[4] = {bf2f(m4.x), bf2f(m4.y), bf2f(m4.z), bf2f(m4.w)};
      const uint4 fv = *reinterpret_cast<const uint4*>(&f_bf[row][co * 8]);
      float fc[8];
      fc[0] = __uint_as_float(fv.x << 16); fc[1] = __uint_as_float(fv.x & 0xffff0000u);
      fc[2] = __uint_as_float(fv.y << 16); fc[3] = __uint_as_float(fv.y & 0xffff0000u);
      fc[4] = __uint_as_float(fv.z << 16); fc[5] = __uint_as_float(fv.z & 0xffff0000u);
      fc[6] = __uint_as_float(fv.w << 16); fc[7] = __uint_as_float(fv.w & 0xffff0000u);
#pragma unroll
      for (int i = 0; i < 4; ++i)
#pragma unroll
        for (int j = 0; j < 8; ++j) acc[i][j] += mv[i] * fc[j];
    }
    unsigned short* Eq = E + (size_t)(q0 + q) * 2048;
#pragma unroll
    for (int i = 0; i < 4; ++i) {
      const int mid = mg * 4 + i;
      uint4 o;
      o.x = (unsigned)f2bf(acc[i][0]) | ((unsigned)f2bf(acc[i][1]) << 16);
      o.y = (unsigned)f2bf(acc[i][2]) | ((unsigned)f2bf(acc[i][3]) << 16);
      o.z = (unsigned)f2bf(acc[i][4]) | ((unsigned)f2bf(acc[i][5]) << 16);
      o.w = (unsigned)f2bf(acc[i][6]) | ((unsigned)f2bf(acc[i][7]) << 16);
      *reinterpret_cast<uint4*>(&Eq[mid * 64 + co * 8]) = o;
    }
  }
}

// ---------------------------------------------------------------------------
// Kernel 3/4: MFMA GEMM  C = act(A[M,KDIM]bf16 @ Bt[N,KDIM]^T + bias)
// 64x64 tile (4 waves x 32x32), BK=128, global_load_lds width-16 staging,
// XOR chunk swizzle for conflict-free ds_read_b128. SWIZZLE=true: an
// E-slab's 4 n-tiles land temporally adjacent on one XCD (blockIdx%8
// round-robin) -> slab HBM-read once, L2 re-reads. 512 blocks = 2/CU keeps
// inter-block overlap across barrier drains (R14: 1/CU regressed).
// ---------------------------------------------------------------------------
template <int KDIM, bool RELU, bool OUTBF16, bool SWIZZLE>
__global__ __launch_bounds__(256) void gemm_mfma(
    const unsigned short* __restrict__ A,   // [M][KDIM] bf16
    const unsigned short* __restrict__ Bt,  // [N][KDIM] bf16
    const float* __restrict__ bias,
    void* __restrict__ Cout, int ldc) {
  __shared__ __align__(16) unsigned short Al[64 * 128];  // 16 KB
  __shared__ __align__(16) unsigned short Bl[64 * 128];  // 16 KB
  const int tid  = threadIdx.x;
  int m0, n0;
  if (SWIZZLE) {
    const int L    = blockIdx.x;
    const int slot = L >> 3;
    m0 = ((L & 7) * 16 + (slot >> 2)) * 64;
    n0 = (slot & 3) * 64;
  } else {
    m0 = blockIdx.x * 64;
    n0 = blockIdx.y * 64;
  }
  const int wv   = tid >> 6, lane = tid & 63;
  const int quad = lane >> 4, s = lane & 15;
  const int moff = (wv & 1) * 32, noff = (wv >> 1) * 32;
  const int lr   = lane >> 4, lc = lane & 15;

  floatx4 acc[2][2] = {{{0.f,0.f,0.f,0.f},{0.f,0.f,0.f,0.f}},
                       {{0.f,0.f,0.f,0.f},{0.f,0.f,0.f,0.f}}};

  for (int k0 = 0; k0 < KDIM; k0 += 128) {
#pragma unroll
    for (int t = 0; t < 4; ++t) {
      const int R0 = wv * 16 + t * 4;          // wave-uniform base row
      const int r  = R0 + lr;
      const int gc = lc ^ (r & 7);
      load_lds16(A  + (size_t)(m0 + r) * KDIM + k0 + gc * 8, &Al[R0 * 128]);
      load_lds16(Bt + (size_t)(n0 + r) * KDIM + k0 + gc * 8, &Bl[R0 * 128]);
    }
    __syncthreads();
#pragma unroll
    for (int h = 0; h < 4; ++h) {
      bf16x8 af[2], bfr[2];
#pragma unroll
      for (int i = 0; i < 2; ++i) {
        const int r = moff + i * 16 + s;
        af[i] = *reinterpret_cast<const bf16x8*>(
            &Al[(size_t)r * 128 + ((((h << 2) | quad) ^ (r & 7)) << 3)]);
      }
#pragma unroll
      for (int j = 0; j < 2; ++j) {
        const int r = noff + j * 16 + s;
        bfr[j] = *reinterpret_cast<const bf16x8*>(
            &Bl[(size_t)r * 128 + ((((h << 2) | quad) ^ (r & 7)) << 3)]);
      }
#pragma unroll
      for (int i = 0; i < 2; ++i)
#pragma unroll
        for (int j = 0; j < 2; ++j)
          acc[i][j] = __builtin_amdgcn_mfma_f32_16x16x32_bf16(af[i], bfr[j], acc[i][j], 0, 0, 0);
    }
    __syncthreads();
  }

#pragma unroll
  for (int i = 0; i < 2; ++i)
#pragma unroll
    for (int j = 0; j < 2; ++j) {
      const int col = n0 + noff + j * 16 + s;
      const float bv = bias[col];
#pragma unroll
      for (int r = 0; r < 4; ++r) {
        const int row = m0 + moff + i * 16 + quad * 4 + r;
        float v = acc[i][j][r] + bv;
        if (RELU) v = fmaxf(v, 0.f);
        if (OUTBF16)
          ((unsigned short*)Cout)[(size_t)row * ldc + col] = f2bf(v);
        else
          ((float*)Cout)[(size_t)row * ldc + col] = v;
      }
    }
}

// ---------------------------------------------------------------------------
extern "C" void kernel_launch(void* const* d_in, const int* in_sizes, int n_in,
                              void* d_out, int out_size, void* d_ws, size_t ws_size,
                              hipStream_t stream) {
  const float* keys   = (const float*)d_in[0];
  const float* points = (const float*)d_in[1];
  const float* feats  = (const float*)d_in[2];
  const float* wc0_W  = (const float*)d_in[3];
  const float* wc0_b  = (const float*)d_in[4];
  const float* wc1_W  = (const float*)d_in[5];
  const float* wc1_b  = (const float*)d_in[6];
  const float* wc2_W  = (const float*)d_in[7];
  const float* wc2_b  = (const float*)d_in[8];
  const float* fc0_W  = (const float*)d_in[9];
  const float* fc0_b  = (const float*)d_in[10];
  const float* fc1_W  = (const float*)d_in[11];
  const float* fc1_b  = (const float*)d_in[12];
  float* out = (float*)d_out;

  const int M = BATCH * KQ;   // 8192
  char* ws = (char*)d_ws;
  unsigned short* E    = (unsigned short*)(ws);                    // 32 MB
  unsigned short* H16  = (unsigned short*)(ws + (size_t)33554432); //  4 MB
  unsigned short* W0T  = (unsigned short*)(ws + (size_t)37748736); //  1 MB
  unsigned short* W1T  = (unsigned short*)(ws + (size_t)38797312); // 64 KB
  int*            nidx = (int*)(ws + (size_t)38862848);            // 512 KB

  select_topk<<<M, 256, 0, stream>>>(keys, points, nidx);
  edge_prep<<<M / QPB, 256, 0, stream>>>(keys, points, feats, nidx,
                                         wc0_W, wc0_b, wc1_W, wc1_b, wc2_W, wc2_b,
                                         fc0_W, fc1_W, W0T, W1T, E);
  gemm_mfma<2048, true,  true,  true ><<<512, 256, 0, stream>>>(E, W0T, fc0_b, H16, 256);
  gemm_mfma<256,  false, false, false><<<dim3(M / 64, 2), 256, 0, stream>>>(H16, W1T, fc1_b, out, 128);
}